// Round 3
// baseline (131.511 us; speedup 1.0000x reference)
//
#include <hip/hip_runtime.h>
#include <hip/hip_bf16.h>

// AbsolutePositionEncoding: out[b][s][e] = E[s>>3][e]
//   b in [0,64), s in [0,2048), e in [0,256), ALL FP32.
// Output: 64*2048*256 = 33,554,432 fp32 = 134 MB. Pure broadcast-write,
// write-bandwidth-bound. float4 = 16 B/lane, perfectly coalesced.
//
// ROUND-2 LESSON (dtype forensics): storage is fp32 per the documented
// contract ("float32 -> const float*"), even though the harness label says
// "bf16" (ref VALUES are bf16-quantized; max|ref|=4.4375 is exactly
// 7-mantissa-bit). The all-bf16 hypothesis is disproven: round-2's byte
// placement was exact under it yet absmax=7.05; the observed 6.16/7.05/4.4375
// sequence matches fp32 buffers with my 16-byte chunks landing at half-size
// row offsets + a zero tail. Input order is the documented dict order:
//   d_in[0] = x (64x2048 fp32, unused), d_in[1] = E (512x256 fp32).

constexpr unsigned BATCH       = 64;
constexpr unsigned SEQ         = 2048;
constexpr unsigned EDIM        = 256;
constexpr unsigned VEC_PER_ROW = EDIM / 4;                   // 64 float4 per (b,s) row
constexpr unsigned TOTAL_VEC   = BATCH * SEQ * VEC_PER_ROW;  // 8,388,608 float4 stores

__global__ __launch_bounds__(256)
void ape_broadcast_kernel(const float4* __restrict__ E, float4* __restrict__ out) {
    // One float4 store per thread; consecutive lanes -> consecutive 16B chunks
    // -> 1 KiB/wave coalesced stores.
    unsigned v   = blockIdx.x * blockDim.x + threadIdx.x;  // < 8.4M, fits u32
    unsigned e4  = v & (VEC_PER_ROW - 1);   // which 4-elem group within the row
    unsigned row = v >> 6;                  // flat (b*SEQ + s)
    unsigned s   = row & (SEQ - 1);
    unsigned obj = s >> 3;                  // token -> object index (s / 8)
    out[v] = E[obj * VEC_PER_ROW + e4];     // E rows are L2-hot (512 KB total)
}

extern "C" void kernel_launch(void* const* d_in, const int* in_sizes, int n_in,
                              void* d_out, int out_size, void* d_ws, size_t ws_size,
                              hipStream_t stream) {
    // Documented dict order: d_in[0] = x (unused), d_in[1] = E_absolute_position.
    const float4* E = (const float4*)d_in[1];
    float4* out     = (float4*)d_out;

    constexpr unsigned BLOCK = 256;
    constexpr unsigned GRID  = TOTAL_VEC / BLOCK;  // 32768 blocks
    ape_broadcast_kernel<<<GRID, BLOCK, 0, stream>>>(E, out);
}